// Round 10
// baseline (62.194 us; speedup 1.0000x reference)
//
#include <hip/hip_runtime.h>

#define IW 512
#define IH 512
#define NPIX (IH * IW)
#define NK 6            // steps 1..6 (step 0 is exact identity)
#define GROUPS 8        // group == bid&7 == XCD -> 3 planes per XCD, L2-resident
#define PPT 3
#define LROW 520        // 4 guard + 512 data + 4 guard
#define GOFF 4

typedef float f4v __attribute__((ext_vector_type(4)));
typedef float f2v __attribute__((ext_vector_type(2)));

struct RowTap { int rowA; float t0, t1; };

// Row taps for one step (block-uniform). Branch-free remap zeroes weights of
// out-of-range tap rows (vertical zero-pad). The 1/7 mean scale is folded in.
__device__ inline RowTap row_prep(float inv, float yf) {
    const float ysv = fmaf(yf, inv, 256.0f);
    const float fy  = floorf(ysv);
    const float wy  = ysv - fy;
    const int y0 = (int)fy;
    const int yb = min(max(y0, 0), IH - 2);
    const float t0 = (yb == y0 ? 1.0f - wy : 0.0f) + (yb == y0 + 1 ? wy : 0.0f);
    const float t1 = (yb + 1 == y0 ? 1.0f - wy : 0.0f) + (yb + 1 == y0 + 1 ? wy : 0.0f);
    RowTap rt;
    rt.t0 = t0 * (1.0f / 7.0f);   // staged lines carry the /7
    rt.t1 = t1 * (1.0f / 7.0f);
    rt.rowA = yb * IW;
    return rt;
}

// issue 6 row loads + 2 identity loads for one plane into registers
#define STAGE_LOAD(base_) do {                                  \
    const float* __restrict__ _b = (base_);                     \
    a0 = *(const f4v*)(_b + r0.rowA + cq);                      \
    b0 = *(const f4v*)(_b + r0.rowA + IW + cq);                 \
    a1 = *(const f4v*)(_b + r1.rowA + cq);                      \
    b1 = *(const f4v*)(_b + r1.rowA + IW + cq);                 \
    a2 = *(const f4v*)(_b + r2.rowA + cq);                      \
    b2 = *(const f4v*)(_b + r2.rowA + IW + cq);                 \
    nId.x = _b[idoff];                                          \
    nId.y = _b[idoff + 256];                                    \
} while (0)

// row-lerp the staged registers (pk-fma) and publish into LDS buffer B
#define STAGE_WRITE(B) do {                                     \
    *(f4v*)&rrow[B][woff]            = r0.t0 * a0 + r0.t1 * b0; \
    *(f4v*)&rrow[B][woff + 2 * LROW] = r1.t0 * a1 + r1.t1 * b1; \
    *(f4v*)&rrow[B][woff + 4 * LROW] = r2.t0 * a2 + r2.t1 * b2; \
} while (0)

// horizontal lerp for both owned pixels (packed f32), NT store
#define COMPUTE_STORE(B, cId_, op_) do {                        \
    f2v acc = (cId_) * (1.0f / 7.0f);                           \
    _Pragma("unroll")                                           \
    for (int k = 0; k < NK; ++k) {                              \
        f2v v0, v1;                                             \
        v0.x = rrow[B][offA[k]];                                \
        v1.x = rrow[B][offA[k] + 1];                            \
        v0.y = rrow[B][offB[k]];                                \
        v1.y = rrow[B][offB[k] + 1];                            \
        acc = __builtin_elementwise_fma(w0v[k], v0,             \
              __builtin_elementwise_fma(w1v[k], v1, acc));      \
    }                                                           \
    float* _o = (op_);                                          \
    __builtin_nontemporal_store(acc.x, _o);                     \
    __builtin_nontemporal_store(acc.y, _o + 256);               \
} while (0)

__global__ __launch_bounds__(256, 6) void zoomblur_kernel(
    const float* __restrict__ img,
    const float* __restrict__ zoomf,
    float* __restrict__ out)
{
    __shared__ float rrow[2][NK * LROW];   // 25 KB: double-buffered 6 lines

    const int tid   = threadIdx.x;
    const int bid   = blockIdx.x;
    const int group = bid & (GROUPS - 1);   // == XCD (round-robin dispatch)
    const int y     = bid >> 3;             // one output row per block

    const float zf = 0.85f + 0.30f * zoomf[0];
    const float dz = zf - 1.0f;
    const float yf  = (float)y - 256.0f;
    // split-pixel ownership: x = tid and x = tid+256
    const float xfA = (float)tid - 256.0f;
    const float xfB = (float)tid;

    float invs[NK];
#pragma unroll
    for (int s = 1; s <= NK; ++s)
        invs[s - 1] = __builtin_amdgcn_rcpf(fmaf((float)s * (1.0f / 6.0f), dz, 1.0f));

    // per-thread column taps; guard-zero: clamp into zeroed guard slots.
    // w0/w1 packed {pixelA, pixelB} for v_pk_fma_f32 compute.
    int offA[NK], offB[NK];
    f2v w0v[NK], w1v[NK];
#pragma unroll
    for (int k = 0; k < NK; ++k) {
        const float inv = invs[k];
        const float xsA = fmaf(xfA, inv, 256.0f);
        const float xsB = fmaf(xfB, inv, 256.0f);
        const float fxA = floorf(xsA);
        const float fxB = floorf(xsB);
        const float wxA = xsA - fxA;
        const float wxB = xsB - fxB;
        w1v[k].x = wxA;        w1v[k].y = wxB;
        w0v[k].x = 1.0f - wxA; w0v[k].y = 1.0f - wxB;
        const int xA = min(max((int)fxA, -2), IW);   // slots 2..516
        const int xB = min(max((int)fxB, -2), IW);
        offA[k] = k * LROW + GOFF + xA;
        offB[k] = k * LROW + GOFF + xB;
    }

    // staging role: thread stages col-quad cq of lines {sbase, sbase+2, sbase+4}
    const int sbase = tid >> 7;             // 0 or 1
    const int cq    = (tid & 127) << 2;     // 0..508
    const RowTap r0 = row_prep(sbase ? invs[1] : invs[0], yf);
    const RowTap r1 = row_prep(sbase ? invs[3] : invs[2], yf);
    const RowTap r2 = row_prep(sbase ? invs[5] : invs[4], yf);
    const int woff = sbase * LROW + GOFF + cq;

    // zero guard slots of both buffers once (stage writes never touch them)
    if (tid < 96) {
        const int line = tid >> 3;              // 0..11
        const int j    = tid & 7;
        const int slot = (j < 4) ? j : 512 + j; // 0..3, 516..519
        const int buf  = line >= NK;
        const int l    = buf ? line - NK : line;
        rrow[buf][l * LROW + slot] = 0.0f;
    }

    const int idoff = y * IW + tid;
    const size_t pbase = (size_t)(group * PPT) * NPIX;
    const float* __restrict__ ib = img + pbase;
    float* __restrict__       ob = out + pbase;

    f4v a0, b0, a1, b1, a2, b2;
    f2v nId, cId;

    // ---- software pipeline: stage p0 -> [compute p | prefetch p+1] ----
    STAGE_LOAD(ib);                       // plane 0
    cId = nId;
    STAGE_WRITE(0);
    __syncthreads();                      // buf0 ready
    STAGE_LOAD(ib + NPIX);                // plane 1 loads fly over compute 0

    COMPUTE_STORE(0, cId, ob + idoff);
    cId = nId;
    STAGE_WRITE(1);                       // consume plane-1 loads
    __syncthreads();                      // buf1 ready; buf0 reads done
    STAGE_LOAD(ib + 2 * NPIX);            // plane 2 loads fly over compute 1

    COMPUTE_STORE(1, cId, ob + NPIX + idoff);
    cId = nId;
    STAGE_WRITE(0);                       // safe: buf0 reads finished pre-barrier
    __syncthreads();                      // buf0 ready again

    COMPUTE_STORE(0, cId, ob + 2 * NPIX + idoff);
}

extern "C" void kernel_launch(void* const* d_in, const int* in_sizes, int n_in,
                              void* d_out, int out_size, void* d_ws, size_t ws_size,
                              hipStream_t stream) {
    const float* img  = (const float*)d_in[0];
    const float* zoom = (const float*)d_in[1];
    float* out = (float*)d_out;

    dim3 block(256);
    dim3 grid(IH * GROUPS);      // 4096 blocks; bid&7 == XCD, 3 planes each
    zoomblur_kernel<<<grid, block, 0, stream>>>(img, zoom, out);
}

// Round 11
// 21.592 us; speedup vs baseline: 2.8804x; 2.8804x over previous
//
#include <hip/hip_runtime.h>

#define IW 512
#define IH 512
#define NPIX (IH * IW)
#define NK 6            // steps 1..6 (step 0 is exact identity)
#define GROUPS 8        // group == bid&7 == XCD -> 3 planes per XCD, L2-resident
#define PPT 3
#define LROW 520        // 4 guard + 512 data + 4 guard
#define GOFF 4

typedef float f4v __attribute__((ext_vector_type(4)));

struct RowTap { int rowA; float t0, t1; };

// Row taps for one step (block-uniform). Branch-free remap zeroes weights of
// out-of-range tap rows (vertical zero-pad). The 1/7 mean scale is folded in.
__device__ inline RowTap row_prep(float inv, float yf) {
    const float ysv = fmaf(yf, inv, 256.0f);
    const float fy  = floorf(ysv);
    const float wy  = ysv - fy;
    const int y0 = (int)fy;
    const int yb = min(max(y0, 0), IH - 2);
    const float t0 = (yb == y0 ? 1.0f - wy : 0.0f) + (yb == y0 + 1 ? wy : 0.0f);
    const float t1 = (yb + 1 == y0 ? 1.0f - wy : 0.0f) + (yb + 1 == y0 + 1 ? wy : 0.0f);
    RowTap rt;
    rt.t0 = t0 * (1.0f / 7.0f);   // staged lines carry the /7
    rt.t1 = t1 * (1.0f / 7.0f);
    rt.rowA = yb * IW;
    return rt;
}

// issue 6 row loads + 2 identity loads for one plane into registers
#define STAGE_LOAD(base_) do {                                  \
    const float* __restrict__ _b = (base_);                     \
    a0 = *(const f4v*)(_b + r0.rowA + cq);                      \
    b0 = *(const f4v*)(_b + r0.rowA + IW + cq);                 \
    a1 = *(const f4v*)(_b + r1.rowA + cq);                      \
    b1 = *(const f4v*)(_b + r1.rowA + IW + cq);                 \
    a2 = *(const f4v*)(_b + r2.rowA + cq);                      \
    b2 = *(const f4v*)(_b + r2.rowA + IW + cq);                 \
    nIdA = _b[idoff];                                           \
    nIdB = _b[idoff + 256];                                     \
} while (0)

// row-lerp the staged registers and publish into LDS buffer B
#define STAGE_WRITE(B) do {                                     \
    *(f4v*)&rrow[B][woff]            = r0.t0 * a0 + r0.t1 * b0; \
    *(f4v*)&rrow[B][woff + 2 * LROW] = r1.t0 * a1 + r1.t1 * b1; \
    *(f4v*)&rrow[B][woff + 4 * LROW] = r2.t0 * a2 + r2.t1 * b2; \
} while (0)

// horizontal 2-FMA lerp for both owned pixels from LDS buffer B, NT store
#define COMPUTE_STORE(B, cA_, cB_, op_) do {                    \
    float aA = (cA_) * (1.0f / 7.0f);                           \
    float aB = (cB_) * (1.0f / 7.0f);                           \
    _Pragma("unroll")                                           \
    for (int k = 0; k < NK; ++k) {                              \
        const float v0A = rrow[B][offA[k]];                     \
        const float v1A = rrow[B][offA[k] + 1];                 \
        const float v0B = rrow[B][offB[k]];                     \
        const float v1B = rrow[B][offB[k] + 1];                 \
        aA = fmaf(w0A[k], v0A, fmaf(w1A[k], v1A, aA));          \
        aB = fmaf(w0B[k], v0B, fmaf(w1B[k], v1B, aB));          \
    }                                                           \
    float* _o = (op_);                                          \
    __builtin_nontemporal_store(aA, _o);                        \
    __builtin_nontemporal_store(aB, _o + 256);                  \
} while (0)

__global__ __launch_bounds__(256, 4) void zoomblur_kernel(
    const float* __restrict__ img,
    const float* __restrict__ zoomf,
    float* __restrict__ out)
{
    __shared__ float rrow[2][NK * LROW];   // 25 KB: double-buffered 6 lines

    const int tid   = threadIdx.x;
    const int bid   = blockIdx.x;
    const int group = bid & (GROUPS - 1);   // == XCD (round-robin dispatch)
    const int y     = bid >> 3;             // one output row per block

    const float zf = 0.85f + 0.30f * zoomf[0];
    const float dz = zf - 1.0f;
    const float yf  = (float)y - 256.0f;
    // split-pixel ownership: x = tid and x = tid+256
    const float xfA = (float)tid - 256.0f;
    const float xfB = (float)tid;

    float invs[NK];
#pragma unroll
    for (int s = 1; s <= NK; ++s)
        invs[s - 1] = __builtin_amdgcn_rcpf(fmaf((float)s * (1.0f / 6.0f), dz, 1.0f));

    // per-thread column taps; guard-zero: clamp into zeroed guard slots.
    // Plain float arrays, fully unrolled static indexing (registers only).
    int   offA[NK], offB[NK];
    float w0A[NK], w1A[NK], w0B[NK], w1B[NK];
#pragma unroll
    for (int k = 0; k < NK; ++k) {
        const float inv = invs[k];
        const float xsA = fmaf(xfA, inv, 256.0f);
        const float xsB = fmaf(xfB, inv, 256.0f);
        const float fxA = floorf(xsA);
        const float fxB = floorf(xsB);
        const float wxA = xsA - fxA;
        const float wxB = xsB - fxB;
        w1A[k] = wxA;  w0A[k] = 1.0f - wxA;
        w1B[k] = wxB;  w0B[k] = 1.0f - wxB;
        const int xA = min(max((int)fxA, -2), IW);   // slots 2..516
        const int xB = min(max((int)fxB, -2), IW);
        offA[k] = k * LROW + GOFF + xA;
        offB[k] = k * LROW + GOFF + xB;
    }

    // staging role: thread stages col-quad cq of lines {sbase, sbase+2, sbase+4}
    const int sbase = tid >> 7;             // 0 or 1
    const int cq    = (tid & 127) << 2;     // 0..508
    const RowTap r0 = row_prep(sbase ? invs[1] : invs[0], yf);
    const RowTap r1 = row_prep(sbase ? invs[3] : invs[2], yf);
    const RowTap r2 = row_prep(sbase ? invs[5] : invs[4], yf);
    const int woff = sbase * LROW + GOFF + cq;

    // zero guard slots of both buffers once (stage writes never touch them)
    if (tid < 96) {
        const int line = tid >> 3;              // 0..11
        const int j    = tid & 7;
        const int slot = (j < 4) ? j : 512 + j; // 0..3, 516..519
        const int buf  = line >= NK;
        const int l    = buf ? line - NK : line;
        rrow[buf][l * LROW + slot] = 0.0f;
    }

    const int idoff = y * IW + tid;
    const size_t pbase = (size_t)(group * PPT) * NPIX;
    const float* __restrict__ ib = img + pbase;
    float* __restrict__       ob = out + pbase;

    f4v a0, b0, a1, b1, a2, b2;
    float nIdA, nIdB;

    // ---- software pipeline: stage p0 -> [compute p | prefetch p+1] ----
    STAGE_LOAD(ib);                       // plane 0
    float cIdA = nIdA, cIdB = nIdB;
    STAGE_WRITE(0);
    __syncthreads();                      // buf0 ready
    STAGE_LOAD(ib + NPIX);                // plane 1 loads fly over compute 0

    COMPUTE_STORE(0, cIdA, cIdB, ob + idoff);
    cIdA = nIdA; cIdB = nIdB;
    STAGE_WRITE(1);                       // consume plane-1 loads
    __syncthreads();                      // buf1 ready; buf0 reads done
    STAGE_LOAD(ib + 2 * NPIX);            // plane 2 loads fly over compute 1

    COMPUTE_STORE(1, cIdA, cIdB, ob + NPIX + idoff);
    cIdA = nIdA; cIdB = nIdB;
    STAGE_WRITE(0);                       // safe: buf0 reads finished pre-barrier
    __syncthreads();                      // buf0 ready again

    COMPUTE_STORE(0, cIdA, cIdB, ob + 2 * NPIX + idoff);
}

extern "C" void kernel_launch(void* const* d_in, const int* in_sizes, int n_in,
                              void* d_out, int out_size, void* d_ws, size_t ws_size,
                              hipStream_t stream) {
    const float* img  = (const float*)d_in[0];
    const float* zoom = (const float*)d_in[1];
    float* out = (float*)d_out;

    dim3 block(256);
    dim3 grid(IH * GROUPS);      // 4096 blocks; bid&7 == XCD, 3 planes each
    zoomblur_kernel<<<grid, block, 0, stream>>>(img, zoom, out);
}

// Round 12
// 19.510 us; speedup vs baseline: 3.1878x; 1.1067x over previous
//
#include <hip/hip_runtime.h>

#define IW 512
#define IH 512
#define NPIX (IH * IW)
#define NK 6            // steps 1..6 (step 0 is exact identity)
#define GROUPS 8        // group == bid&7 == XCD -> 3 planes per XCD, L2-resident
#define PPT 3
#define LROW 520        // 4 guard + 512 data + 4 guard
#define GOFF 4

typedef float f4v __attribute__((ext_vector_type(4)));

struct RowTap { int rowA; float t0, t1; };

// Row taps for one step (block-uniform). Branch-free remap zeroes weights of
// out-of-range tap rows (vertical zero-pad). The 1/7 mean scale is folded in.
__device__ inline RowTap row_prep(float inv, float yf) {
    const float ysv = fmaf(yf, inv, 256.0f);
    const float fy  = floorf(ysv);
    const float wy  = ysv - fy;
    const int y0 = (int)fy;
    const int yb = min(max(y0, 0), IH - 2);
    const float t0 = (yb == y0 ? 1.0f - wy : 0.0f) + (yb == y0 + 1 ? wy : 0.0f);
    const float t1 = (yb + 1 == y0 ? 1.0f - wy : 0.0f) + (yb + 1 == y0 + 1 ? wy : 0.0f);
    RowTap rt;
    rt.t0 = t0 * (1.0f / 7.0f);   // staged lines carry the /7
    rt.t1 = t1 * (1.0f / 7.0f);
    rt.rowA = yb * IW;
    return rt;
}

// issue 6 row loads + 2 identity loads for plane at base_ into the a-set
#define STAGE_LOAD(base_, idA_, idB_) do {                      \
    const float* __restrict__ _b = (base_);                     \
    a0 = *(const f4v*)(_b + r0.rowA + cq);                      \
    b0 = *(const f4v*)(_b + r0.rowA + IW + cq);                 \
    a1 = *(const f4v*)(_b + r1.rowA + cq);                      \
    b1 = *(const f4v*)(_b + r1.rowA + IW + cq);                 \
    a2 = *(const f4v*)(_b + r2.rowA + cq);                      \
    b2 = *(const f4v*)(_b + r2.rowA + IW + cq);                 \
    idA_ = _b[idoff];                                           \
    idB_ = _b[idoff + 256];                                     \
} while (0)

// row-lerp the arrived a-set into the L registers (frees the a-set)
#define LERP_L() do {                                           \
    L0 = r0.t0 * a0 + r0.t1 * b0;                               \
    L1 = r1.t0 * a1 + r1.t1 * b1;                               \
    L2 = r2.t0 * a2 + r2.t1 * b2;                               \
} while (0)

// publish the L registers into LDS buffer B
#define STAGE_WRITE(B) do {                                     \
    *(f4v*)&rrow[B][woff]            = L0;                      \
    *(f4v*)&rrow[B][woff + 2 * LROW] = L1;                      \
    *(f4v*)&rrow[B][woff + 4 * LROW] = L2;                      \
} while (0)

// horizontal lerp for both owned pixels from LDS buffer B, NT store
#define COMPUTE_STORE(B, cA_, cB_, op_) do {                    \
    float aA = (cA_) * (1.0f / 7.0f);                           \
    float aB = (cB_) * (1.0f / 7.0f);                           \
    _Pragma("unroll")                                           \
    for (int k = 0; k < NK; ++k) {                              \
        const float v0A = rrow[B][offA[k]];                     \
        const float v1A = rrow[B][offA[k] + 1];                 \
        const float v0B = rrow[B][offB[k]];                     \
        const float v1B = rrow[B][offB[k] + 1];                 \
        aA = fmaf(wxA[k], v1A - v0A, aA + v0A);                 \
        aB = fmaf(wxB[k], v1B - v0B, aB + v0B);                 \
    }                                                           \
    float* _o = (op_);                                          \
    __builtin_nontemporal_store(aA, _o);                        \
    __builtin_nontemporal_store(aB, _o + 256);                  \
} while (0)

__global__ __launch_bounds__(256, 6) void zoomblur_kernel(
    const float* __restrict__ img,
    const float* __restrict__ zoomf,
    float* __restrict__ out)
{
    __shared__ float rrow[2][NK * LROW];   // 25 KB: double-buffered 6 lines

    const int tid   = threadIdx.x;
    const int bid   = blockIdx.x;
    const int group = bid & (GROUPS - 1);   // == XCD (round-robin dispatch)
    const int y     = bid >> 3;             // one output row per block

    const float zf = 0.85f + 0.30f * zoomf[0];
    const float dz = zf - 1.0f;
    const float yf  = (float)y - 256.0f;
    // split-pixel ownership: x = tid and x = tid+256
    const float xfA = (float)tid - 256.0f;
    const float xfB = (float)tid;

    float invs[NK];
#pragma unroll
    for (int s = 1; s <= NK; ++s)
        invs[s - 1] = __builtin_amdgcn_rcpf(fmaf((float)s * (1.0f / 6.0f), dz, 1.0f));

    // per-thread column taps; guard-zero: clamp into zeroed guard slots,
    // keep plain interior weights (lerp form: one wx per pixel per step)
    int   offA[NK], offB[NK];
    float wxA[NK], wxB[NK];
#pragma unroll
    for (int k = 0; k < NK; ++k) {
        const float inv = invs[k];
        const float xsA = fmaf(xfA, inv, 256.0f);
        const float xsB = fmaf(xfB, inv, 256.0f);
        const float fxA = floorf(xsA);
        const float fxB = floorf(xsB);
        wxA[k] = xsA - fxA;
        wxB[k] = xsB - fxB;
        const int xA = min(max((int)fxA, -2), IW);   // slots 2..516
        const int xB = min(max((int)fxB, -2), IW);
        offA[k] = k * LROW + GOFF + xA;
        offB[k] = k * LROW + GOFF + xB;
    }

    // staging role: thread stages col-quad cq of lines {sbase, sbase+2, sbase+4}
    const int sbase = tid >> 7;             // 0 or 1
    const int cq    = (tid & 127) << 2;     // 0..508
    const RowTap r0 = row_prep(sbase ? invs[1] : invs[0], yf);
    const RowTap r1 = row_prep(sbase ? invs[3] : invs[2], yf);
    const RowTap r2 = row_prep(sbase ? invs[5] : invs[4], yf);
    const int woff = sbase * LROW + GOFF + cq;

    // zero guard slots of both buffers once (stage writes never touch them)
    if (tid < 96) {
        const int line = tid >> 3;              // 0..11
        const int j    = tid & 7;
        const int slot = (j < 4) ? j : 512 + j; // 0..3, 516..519
        const int buf  = line >= NK;
        const int l    = buf ? line - NK : line;
        rrow[buf][l * LROW + slot] = 0.0f;
    }

    const int idoff = y * IW + tid;
    const size_t pbase = (size_t)(group * PPT) * NPIX;
    const float* __restrict__ ib = img + pbase;
    float* __restrict__       ob = out + pbase;

    f4v a0, b0, a1, b1, a2, b2;   // in-flight load set (one plane deep)
    f4v L0, L1, L2;               // lerped lines ready to publish
    float idA0, idB0, idA1, idB1, idA2, idB2;

    // ---- deepened pipeline: plane p+1's loads are issued BEFORE the
    //      barrier/compute of plane p, giving them write+bar+compute of
    //      latency cover (cold-HBM ~900 cyc; R9's window was compute-only) ----
    STAGE_LOAD(ib, idA0, idB0);           // plane 0
    LERP_L();                             // waits plane-0 loads
    STAGE_LOAD(ib + NPIX, idA1, idB1);    // plane 1 in flight
    STAGE_WRITE(0);
    __syncthreads();                      // buf0 ready

    COMPUTE_STORE(0, idA0, idB0, ob + idoff);
    LERP_L();                             // waits plane-1 loads (long window)
    STAGE_LOAD(ib + 2 * NPIX, idA2, idB2); // plane 2 in flight
    STAGE_WRITE(1);
    __syncthreads();                      // buf1 ready; buf0 reads done

    COMPUTE_STORE(1, idA1, idB1, ob + NPIX + idoff);
    LERP_L();                             // waits plane-2 loads
    STAGE_WRITE(0);                       // safe: buf0 reads finished pre-barrier
    __syncthreads();                      // buf0 ready again

    COMPUTE_STORE(0, idA2, idB2, ob + 2 * NPIX + idoff);
}

extern "C" void kernel_launch(void* const* d_in, const int* in_sizes, int n_in,
                              void* d_out, int out_size, void* d_ws, size_t ws_size,
                              hipStream_t stream) {
    const float* img  = (const float*)d_in[0];
    const float* zoom = (const float*)d_in[1];
    float* out = (float*)d_out;

    dim3 block(256);
    dim3 grid(IH * GROUPS);      // 4096 blocks; bid&7 == XCD, 3 planes each
    zoomblur_kernel<<<grid, block, 0, stream>>>(img, zoom, out);
}